// Round 12
// baseline (1720.236 us; speedup 1.0000x reference)
//
#include <hip/hip_runtime.h>

typedef unsigned short u16;
typedef unsigned int   u32;
typedef unsigned long long u64;
typedef __attribute__((ext_vector_type(8))) short bf16x8;
typedef __attribute__((ext_vector_type(16))) float f32x16;
typedef __attribute__((ext_vector_type(4))) float f32x4;
typedef __attribute__((ext_vector_type(4))) u32 u32x4;

#define T_SEQ 300

// workspace layout (bytes) — all offsets 16B-aligned
#define OFF_WP   0u            // packed A-frag weights bf16: 256 jp * 42 kk * 64 lanes * 16B = 11,010,048
#define OFF_BP   11010048u     // packed bias f32 [512 j][16 g] = 32,768
#define OFF_XB   11042816u     // x bf16 K-slot layout: 300*128*192*2 = 14,745,600
#define OFF_H    25788416u     // h arena bf16: 301 * [bq 4][jgh 32][n 32][jl 16] * 2B = 39,452,672
#define OFF_FL   65241088u     // flags[128 * 32] — ONE 128B line per flag (false-sharing fix)

__device__ __forceinline__ float bf2f(u16 u){ union { u32 u; float f; } v; v.u = ((u32)u) << 16; return v.f; }
__device__ __forceinline__ u16 f2bf(float f){
  union { float f; u32 u; } v; v.f = f;
  u32 r = v.u + 0x7fffu + ((v.u >> 16) & 1u);
  return (u16)(r >> 16);
}
__device__ __forceinline__ float sigf(float x){ return 1.f / (1.f + __expf(-x)); }
__device__ __forceinline__ float tanh_f(float x){ return 1.f - 2.f / (1.f + __expf(2.f * x)); }

// ---------------------------------------------------------------------------
// prep: pack fp32 weights into 32x32x16 MFMA *A-operand* fragments (weights on
// the M side; gates in M). M-row m -> (jj=(m>>2)&1, g=(m&3)+4*(m>>3)); with the
// C/D layout row=(reg&3)+8*(reg>>2)+4*(lane>>5) this makes acc[reg]=gate reg
// for j=jp*2+(lane>>5) per lane. A[m][k]: m=lane&31, k=kk*16+(lane>>5)*8+i
// (same per-lane k-convention used for the B pack — a uniform k-permutation
// cancels between operands). K-space (672): [0,512)=hidden, [512,672)=
// 5 parts * 32 slots (slot (p,cc,ii): d=cc*8+ii for cc<3; cc==3: ii<2 -> ZERO
// weight (data dups x[22],x[23]), ii>=2 -> d=22+ii). g<15: part p=g/3, type
// g%3 (own part only); g==15: shared o-gate (Who/Wxo, all parts).
// Also: bias pack [j][16], zero h[0], reset flags (padded, 4096 ints).
// ---------------------------------------------------------------------------
__global__ void prep(const float* __restrict__ Wx, const float* __restrict__ Wh,
                     const float* __restrict__ bg, const float* __restrict__ Wxo,
                     const float* __restrict__ Who, const float* __restrict__ bo,
                     u16* __restrict__ Wp, float* __restrict__ bpack,
                     u16* __restrict__ h0, int* __restrict__ flags)
{
  int w = blockIdx.x * 256 + threadIdx.x;     // 0 .. 688127 = 256 jp * 42 kk * 64 lanes

  if (w < 8192) {
    u32x4 z = {0u, 0u, 0u, 0u};
    ((u32x4*)h0)[w] = z;                      // zero h[0] (128*512 bf16)
    int j = w >> 4, g = w & 15;
    float bv;
    if (g < 15) { int p = g / 3, t3 = g - p * 3; bv = bg[p * 1536 + t3 * 512 + j]; }
    else bv = bo[j];
    bpack[w] = bv;
  }
  if (w < 4096) flags[w] = 0;                 // 128 flags * 32-int (128B) stride

  int lane = w & 63, rem = w >> 6;
  int kk = rem % 42, jp = rem / 42;           // jp 0..255
  int m = lane & 31, hi = lane >> 5;
  int jj = (m >> 2) & 1, g = (m & 3) + 4 * (m >> 3);
  int j = jp * 2 + jj;
  union { u16 s[8]; u32x4 v; } o;
  #pragma unroll
  for (int i = 0; i < 8; ++i) {
    int k = kk * 16 + hi * 8 + i;
    float val = 0.f;
    if (g < 15) {
      int p = g / 3, t3 = g - p * 3, col = t3 * 512 + j;
      if (k < 512) val = Wh[(p * 512 + k) * 1536 + col];
      else {
        int s = k - 512, px = s >> 5, cc = (s >> 3) & 3, ii = s & 7;
        int d = (cc < 3) ? cc * 8 + ii : ((ii < 2) ? -1 : 22 + ii);
        if (px == p && d >= 0) val = Wx[(p * 30 + d) * 1536 + col];
      }
    } else {
      if (k < 512) val = Who[k * 512 + j];
      else {
        int s = k - 512, px = s >> 5, cc = (s >> 3) & 3, ii = s & 7;
        int d = (cc < 3) ? cc * 8 + ii : ((ii < 2) ? -1 : 22 + ii);
        if (d >= 0) val = Wxo[(px * 30 + d) * 512 + j];
      }
    }
    o.s[i] = f2bf(val);
  }
  *(u32x4*)(Wp + ((size_t)(jp * 42 + kk) * 64 + lane) * 8) = o.v;
}

// ---------------------------------------------------------------------------
// prep_x: fp32 x [5][128][300][30] -> bf16 xb[t][bglob][slot] (slot 0..191,
// slots 160..191 zero pad). One thread = one 8-slot chunk (16B store).
// ---------------------------------------------------------------------------
__global__ void prep_x(const float* __restrict__ x, u16* __restrict__ xb)
{
  int w = blockIdx.x * 256 + threadIdx.x;     // 0 .. 921599
  int cx = w % 24, rem = w / 24;
  int bglob = rem % 128, t = rem / 128;
  union { u16 s[8]; u32x4 v; } o;
  int s0 = cx << 3;
  if (s0 >= 160) {
    u32x4 z = {0u, 0u, 0u, 0u}; o.v = z;
  } else {
    int p = s0 >> 5, cc = (s0 >> 3) & 3;
    const float* row = x + ((size_t)(p * 128 + bglob) * 300 + t) * 30;
    #pragma unroll
    for (int i = 0; i < 8; ++i) {
      int d = (cc < 3) ? cc * 8 + i : 22 + i;
      o.s[i] = f2bf(row[d]);
    }
  }
  *(u32x4*)(xb + (size_t)w * 8) = o.v;
}

// Distributed readiness: two lanes poll each of the 32 flags of one batch
// quarter. Each flag owns a full 128B line -> 32 parallel line reads, no
// producer-side line ping-pong. SINGLE poller wave per block (round-7 showed
// 8 pollers/block re-creates the flag-line read storm).
__device__ __forceinline__ void wait_flags32(const int* f, int t)
{
  int l = threadIdx.x & 31;
  for (;;) {
    int v = __hip_atomic_load(&f[l * 32], __ATOMIC_RELAXED, __HIP_MEMORY_SCOPE_AGENT);
    if (__all(v >= t)) break;
  }
}

// ---------------------------------------------------------------------------
// Persistent part-LSTM, gate-in-lane formulation — round-11 kernel (best:
// 1369us plstm) + dual accumulator chains, made ADMISSIBLE by
// __launch_bounds__(512, 1):
//  * (512,1) raises the per-wave register budget to 512 (physically nothing
//    changes: 128 blocks on 256 CUs never needed 2 blocks/CU; cooperative
//    co-residency still trivially satisfied). Round 10 proved dual-acc at
//    (512,2) spills (WRITE_SIZE 80->86MB) — budget was razor-thin with the
//    168-reg resident afr.
//  * even/odd kk accumulate into acc_a/acc_b, halving the dependent MFMA
//    chain (42 serial MFMAs -> 2x21) that only 2 waves/SIMD partially hide;
//    summed once before the elementwise.
// Admissibility gate for this round: WRITE_SIZE stays ~79.5MB (no spill).
//
// All else identical to round 11: publisher-exempt x-staging (wave 0's
// publish drain overlaps waves 1-7's staging), wave-0-only flag poll,
// line-exclusive flags (128B each), block-major hall publish
// [t][bq:4][jgh:32][n:32][jl:16] (8 exclusive lines/producer), round-6
// linear-contiguous h-stage (best L2 streaming; LDS write conflicts proven
// hidden).
// ---------------------------------------------------------------------------
__global__ void __launch_bounds__(512, 1)
plstm(const u16* __restrict__ xb, const u16* __restrict__ Wp,
      const float* __restrict__ bpack, u16* hall, int* flags,
      const float* __restrict__ fcw, const float* __restrict__ fcb,
      float* __restrict__ out)
{
  __shared__ __align__(16) u16 Hsh[32 * 512];   // 32 KB: h rows [n][64 chunks] (xor-swizzled)
  __shared__ __align__(16) u16 Xsh[32 * 256];   // 16 KB: x rows [n][32 chunks] (xor-swizzled)
  __shared__ __align__(16) u16 hbuf[32 * 16];   // 1 KB: h publish staging [n][jl]

  const int tid  = threadIdx.x;
  const int lane = tid & 63;
  const int wv   = tid >> 6;          // 8 waves
  const int n    = lane & 31;         // batch row within quarter
  const int hi   = lane >> 5;         // k-half / j-parity
  const int bq   = blockIdx.x & 3;    // 0..3  (XCD co-location remap)
  const int jgh  = blockIdx.x >> 2;   // 0..31 (16 j each)
  const int jp   = jgh * 8 + wv;      // j-pair 0..255
  const int j    = jp * 2 + hi;       // this lane's hidden col
  int* myflags = flags + bq * 1024;   // 32 flags * 32-int stride

  // resident A-fragments (weights), 42 ksteps x 4 regs — unconditional load
  bf16x8 afr[42];
  {
    const u16* wpb = Wp + ((size_t)jp * 42 * 64 + lane) * 8;
    #pragma unroll
    for (int kk = 0; kk < 42; ++kk)
      afr[kk] = *(const bf16x8*)(wpb + kk * 512);
  }
  float bias[16];
  #pragma unroll
  for (int i = 0; i < 4; ++i)
    *(f32x4*)(bias + i * 4) = *(const f32x4*)(bpack + j * 16 + i * 4);

  float cst[5] = {0.f, 0.f, 0.f, 0.f, 0.f};

  for (int t = 0; t < T_SEQ; ++t) {
    // ---- waves 1-7: stage x[t] rows (own quarter) into LDS, chunk-XOR
    // swizzle. 448 threads cover 768 chunks (2 each, 2nd bounded). Wave 0
    // is EXEMPT: its publish drain from step t-1 overlaps this staging and
    // its path to (A) is empty. ((C) of step t-1 ordered all Xsh reads
    // before these writes.)
    if (wv >= 1) {
      const u16* xsrc = xb + (size_t)(t * 128 + bq * 32) * 192;
      int base = tid - 64;              // 0..447
      #pragma unroll
      for (int i = 0; i < 2; ++i) {
        int c = base + i * 448;         // 0..895, valid < 768 = 32 rows * 24 chunks
        if (c < 768) {
          int b = c / 24, cx = c - b * 24;
          u32x4 v = *(const u32x4*)(xsrc + b * 192 + (cx << 3));
          *(u32x4*)(Xsh + (b << 8) + (((cx ^ b) & 31) << 3)) = v;
        }
      }
    }
    __syncthreads();                      // (A)

    f32x16 acc_a, acc_b;
    #pragma unroll
    for (int i = 0; i < 16; ++i) { acc_a[i] = 0.f; acc_b[i] = 0.f; }

    // ---- K-loop, x part (no h dependency — absorbs inter-block jitter);
    // even/odd kx feed independent accumulator chains.
    #pragma unroll
    for (int kx = 0; kx < 10; ++kx) {
      int c = kx * 2 + hi;                // chunk 0..19
      bf16x8 bf = *(const bf16x8*)(Xsh + (n << 8) + (((c ^ n) & 31) << 3));
      if (kx & 1)
        acc_b = __builtin_amdgcn_mfma_f32_32x32x16_bf16(afr[32 + kx], bf, acc_b, 0, 0, 0);
      else
        acc_a = __builtin_amdgcn_mfma_f32_32x32x16_bf16(afr[32 + kx], bf, acc_a, 0, 0, 0);
    }

    // ---- wave 0 polls own-quarter flags; barrier release ----
    if (wv == 0) wait_flags32(myflags, t);
    __syncthreads();                      // (B0)

    // ---- stage h[t] (own quarter, block-major source, LINEAR in idx) into
    // LDS with the round-1 swizzle. idx rotated by jgh*64 so each block
    // starts at its own output's chunk group (L2-local first).
    {
      const u16* hsrc = hall + (size_t)t * 65536 + bq * 16384;
      #pragma unroll
      for (int i = 0; i < 4; ++i) {
        int idx = (tid + (i << 9) + (jgh << 6)) & 2047;  // 2048 chunks of 16B
        u32x4 v = *(const u32x4*)(hsrc + idx * 8);
        int nn = (idx >> 1) & 31;                        // batch row
        int cx = ((idx >> 6) << 1) | (idx & 1);          // logical chunk
        int phys = (cx & 32) | ((cx ^ nn) & 31);
        *(u32x4*)(Hsh + (nn << 9) + (phys << 3)) = v;
      }
    }
    __syncthreads();                      // (B)

    // ---- K-loop, hidden part; even/odd kk feed independent chains ----
    #pragma unroll
    for (int kk = 0; kk < 32; ++kk) {
      int c = kk * 2 + hi;                // chunk 0..63
      int phys = (c & 32) | ((c ^ n) & 31);
      bf16x8 bf = *(const bf16x8*)(Hsh + (n << 9) + (phys << 3));
      if (kk & 1)
        acc_b = __builtin_amdgcn_mfma_f32_32x32x16_bf16(afr[kk], bf, acc_b, 0, 0, 0);
      else
        acc_a = __builtin_amdgcn_mfma_f32_32x32x16_bf16(afr[kk], bf, acc_a, 0, 0, 0);
    }
    f32x16 acc = acc_a + acc_b;

    // ---- per-lane elementwise: acc[g] = gate g for (j, b) ----
    float cs = 0.f;
    #pragma unroll
    for (int p = 0; p < 5; ++p) {
      float iv = acc[p * 3 + 0] + bias[p * 3 + 0];
      float fv = acc[p * 3 + 1] + bias[p * 3 + 1];
      float gv = acc[p * 3 + 2] + bias[p * 3 + 2];
      cst[p] = sigf(fv) * cst[p] + sigf(iv) * tanh_f(gv);
      cs += cst[p];
    }
    float hv = sigf(acc[15] + bias[15]) * tanh_f(cs);

    // ---- publish h(t+1): LDS transpose -> contiguous 1KB (8 exclusive
    // lines) of agent-scope stores by wave 0; lane-local vmcnt drain; flag.
    // Waves 1-7 fall straight through to next step's x staging (overlap).
    hbuf[(n << 4) + (wv << 1) + hi] = f2bf(hv);
    __syncthreads();                      // (C)
    if (tid < 64) {
      const u16* src = hbuf + tid * 8;    // 16B per lane, linear
      u64 v0 = *(const u64*)(src);
      u64 v1 = *(const u64*)(src + 4);
      u64* dst = (u64*)(hall + (size_t)(t + 1) * 65536 + bq * 16384
                        + jgh * 512 + tid * 8);
      __hip_atomic_store(dst,     v0, __ATOMIC_RELAXED, __HIP_MEMORY_SCOPE_AGENT);
      __hip_atomic_store(dst + 1, v1, __ATOMIC_RELAXED, __HIP_MEMORY_SCOPE_AGENT);
      asm volatile("s_waitcnt vmcnt(0)" ::: "memory");   // wave-0-local drain
      if (tid == 0)
        __hip_atomic_store(&myflags[jgh * 32], t + 1, __ATOMIC_RELAXED, __HIP_MEMORY_SCOPE_AGENT);
    }
  }

  // ---- classifier + log_softmax: blocks 0..63 do 2 batch rows each ----
  if (blockIdx.x >= 64) return;
  for (;;) {
    int v0 = __hip_atomic_load(&flags[lane * 32],        __ATOMIC_RELAXED, __HIP_MEMORY_SCOPE_AGENT);
    int v1 = __hip_atomic_load(&flags[2048 + lane * 32], __ATOMIC_RELAXED, __HIP_MEMORY_SCOPE_AGENT);
    if (__all(min(v0, v1) >= T_SEQ)) break;
  }
  __syncthreads();
  float* fsh = (float*)Hsh;
  const u16* hT = hall + (size_t)T_SEQ * 65536;
  for (int r = 0; r < 2; ++r) {
    int row = blockIdx.x * 2 + r;
    int ks = tid >> 6, c = tid & 63;      // 8 K-slices of 64
    float s = 0.f;
    if (c < 60) {
      // hall element (row, j) -> [row>>5][j>>4][row&31][j&15]
      const u16* hb = hT + (row >> 5) * 16384 + (row & 31) * 16;
      const float* wr = fcw + (size_t)(ks * 64) * 60 + c;
      #pragma unroll 8
      for (int k = 0; k < 64; ++k)
        s += bf2f(hb[(ks * 4 + (k >> 4)) * 512 + (k & 15)]) * wr[k * 60];
    }
    __syncthreads();
    fsh[ks * 64 + c] = s;
    __syncthreads();
    if (tid < 60) {
      float lg = fcb[tid];
      #pragma unroll
      for (int i = 0; i < 8; ++i) lg += fsh[i * 64 + tid];
      fsh[512 + tid] = lg;
    }
    __syncthreads();
    if (tid == 0) {
      float mx = -1e30f;
      for (int i = 0; i < 60; ++i) mx = fmaxf(mx, fsh[512 + i]);
      float sm = 0.f;
      for (int i = 0; i < 60; ++i) sm += __expf(fsh[512 + i] - mx);
      fsh[576] = mx + __logf(sm);
    }
    __syncthreads();
    if (tid < 60) out[row * 60 + tid] = fsh[512 + tid] - fsh[576];
    __syncthreads();
  }
}

extern "C" void kernel_launch(void* const* d_in, const int* in_sizes, int n_in,
                              void* d_out, int out_size, void* d_ws, size_t ws_size,
                              hipStream_t stream)
{
  const float* xin = (const float*)d_in[0];   // [5][128][300][30]
  const float* Wx  = (const float*)d_in[1];   // [5][30][1536]
  const float* Wh  = (const float*)d_in[2];   // [5][512][1536]
  const float* bg  = (const float*)d_in[3];   // [5][1536]
  const float* Wxo = (const float*)d_in[4];   // [150][512]
  const float* Who = (const float*)d_in[5];   // [512][512]
  const float* bo  = (const float*)d_in[6];   // [512]
  const float* fcw = (const float*)d_in[7];   // [512][60]
  const float* fcb = (const float*)d_in[8];   // [60]
  float* out = (float*)d_out;                 // [128][60]

  char* ws = (char*)d_ws;
  u16*   Wp    = (u16*)(ws + OFF_WP);
  float* bpack = (float*)(ws + OFF_BP);
  u16*   xb    = (u16*)(ws + OFF_XB);
  u16*   hall  = (u16*)(ws + OFF_H);
  int*   flags = (int*)(ws + OFF_FL);

  hipLaunchKernelGGL(prep, dim3(2688), dim3(256), 0, stream,
                     Wx, Wh, bg, Wxo, Who, bo, Wp, bpack, hall, flags);
  hipLaunchKernelGGL(prep_x, dim3(3600), dim3(256), 0, stream, xin, xb);

  void* args[] = { (void*)&xb, (void*)&Wp, (void*)&bpack, (void*)&hall,
                   (void*)&flags, (void*)&fcw, (void*)&fcb, (void*)&out };
  hipLaunchCooperativeKernel((void*)plstm, dim3(128), dim3(512), args, 0, stream);
}

// Round 13
// 1431.993 us; speedup vs baseline: 1.2013x; 1.2013x over previous
//
#include <hip/hip_runtime.h>

typedef unsigned short u16;
typedef unsigned int   u32;
typedef unsigned long long u64;
typedef __attribute__((ext_vector_type(8))) short bf16x8;
typedef __attribute__((ext_vector_type(16))) float f32x16;
typedef __attribute__((ext_vector_type(4))) float f32x4;
typedef __attribute__((ext_vector_type(4))) u32 u32x4;

#define T_SEQ 300

// workspace layout (bytes) — all offsets 16B-aligned
#define OFF_WP   0u            // packed A-frag weights bf16: 256 jp * 42 kk * 64 lanes * 16B = 11,010,048
#define OFF_BP   11010048u     // packed bias f32 [512 j][16 g] = 32,768
#define OFF_XB   11042816u     // x bf16 K-slot layout: 300*128*192*2 = 14,745,600
#define OFF_H    25788416u     // h arena bf16: 301 * [bq 4][jgh 32][n 32][jl 16] * 2B = 39,452,672
#define OFF_FL   65241088u     // flags[128 * 32] — ONE 128B line per flag (false-sharing fix)

__device__ __forceinline__ float bf2f(u16 u){ union { u32 u; float f; } v; v.u = ((u32)u) << 16; return v.f; }
__device__ __forceinline__ u16 f2bf(float f){
  union { float f; u32 u; } v; v.f = f;
  u32 r = v.u + 0x7fffu + ((v.u >> 16) & 1u);
  return (u16)(r >> 16);
}
__device__ __forceinline__ float sigf(float x){ return 1.f / (1.f + __expf(-x)); }
__device__ __forceinline__ float tanh_f(float x){ return 1.f - 2.f / (1.f + __expf(2.f * x)); }

// ---------------------------------------------------------------------------
// prep: pack fp32 weights into 32x32x16 MFMA *A-operand* fragments (weights on
// the M side; gates in M). M-row m -> (jj=(m>>2)&1, g=(m&3)+4*(m>>3)); with the
// C/D layout row=(reg&3)+8*(reg>>2)+4*(lane>>5) this makes acc[reg]=gate reg
// for j=jp*2+(lane>>5) per lane. A[m][k]: m=lane&31, k=kk*16+(lane>>5)*8+i
// (same per-lane k-convention used for the B pack — a uniform k-permutation
// cancels between operands). K-space (672): [0,512)=hidden, [512,672)=
// 5 parts * 32 slots (slot (p,cc,ii): d=cc*8+ii for cc<3; cc==3: ii<2 -> ZERO
// weight (data dups x[22],x[23]), ii>=2 -> d=22+ii). g<15: part p=g/3, type
// g%3 (own part only); g==15: shared o-gate (Who/Wxo, all parts).
// Also: bias pack [j][16], zero h[0], reset flags (padded, 4096 ints).
// ---------------------------------------------------------------------------
__global__ void prep(const float* __restrict__ Wx, const float* __restrict__ Wh,
                     const float* __restrict__ bg, const float* __restrict__ Wxo,
                     const float* __restrict__ Who, const float* __restrict__ bo,
                     u16* __restrict__ Wp, float* __restrict__ bpack,
                     u16* __restrict__ h0, int* __restrict__ flags)
{
  int w = blockIdx.x * 256 + threadIdx.x;     // 0 .. 688127 = 256 jp * 42 kk * 64 lanes

  if (w < 8192) {
    u32x4 z = {0u, 0u, 0u, 0u};
    ((u32x4*)h0)[w] = z;                      // zero h[0] (128*512 bf16)
    int j = w >> 4, g = w & 15;
    float bv;
    if (g < 15) { int p = g / 3, t3 = g - p * 3; bv = bg[p * 1536 + t3 * 512 + j]; }
    else bv = bo[j];
    bpack[w] = bv;
  }
  if (w < 4096) flags[w] = 0;                 // 128 flags * 32-int (128B) stride

  int lane = w & 63, rem = w >> 6;
  int kk = rem % 42, jp = rem / 42;           // jp 0..255
  int m = lane & 31, hi = lane >> 5;
  int jj = (m >> 2) & 1, g = (m & 3) + 4 * (m >> 3);
  int j = jp * 2 + jj;
  union { u16 s[8]; u32x4 v; } o;
  #pragma unroll
  for (int i = 0; i < 8; ++i) {
    int k = kk * 16 + hi * 8 + i;
    float val = 0.f;
    if (g < 15) {
      int p = g / 3, t3 = g - p * 3, col = t3 * 512 + j;
      if (k < 512) val = Wh[(p * 512 + k) * 1536 + col];
      else {
        int s = k - 512, px = s >> 5, cc = (s >> 3) & 3, ii = s & 7;
        int d = (cc < 3) ? cc * 8 + ii : ((ii < 2) ? -1 : 22 + ii);
        if (px == p && d >= 0) val = Wx[(p * 30 + d) * 1536 + col];
      }
    } else {
      if (k < 512) val = Who[k * 512 + j];
      else {
        int s = k - 512, px = s >> 5, cc = (s >> 3) & 3, ii = s & 7;
        int d = (cc < 3) ? cc * 8 + ii : ((ii < 2) ? -1 : 22 + ii);
        if (d >= 0) val = Wxo[(px * 30 + d) * 512 + j];
      }
    }
    o.s[i] = f2bf(val);
  }
  *(u32x4*)(Wp + ((size_t)(jp * 42 + kk) * 64 + lane) * 8) = o.v;
}

// ---------------------------------------------------------------------------
// prep_x: fp32 x [5][128][300][30] -> bf16 xb[t][bglob][slot] (slot 0..191,
// slots 160..191 zero pad). One thread = one 8-slot chunk (16B store).
// ---------------------------------------------------------------------------
__global__ void prep_x(const float* __restrict__ x, u16* __restrict__ xb)
{
  int w = blockIdx.x * 256 + threadIdx.x;     // 0 .. 921599
  int cx = w % 24, rem = w / 24;
  int bglob = rem % 128, t = rem / 128;
  union { u16 s[8]; u32x4 v; } o;
  int s0 = cx << 3;
  if (s0 >= 160) {
    u32x4 z = {0u, 0u, 0u, 0u}; o.v = z;
  } else {
    int p = s0 >> 5, cc = (s0 >> 3) & 3;
    const float* row = x + ((size_t)(p * 128 + bglob) * 300 + t) * 30;
    #pragma unroll
    for (int i = 0; i < 8; ++i) {
      int d = (cc < 3) ? cc * 8 + i : 22 + i;
      o.s[i] = f2bf(row[d]);
    }
  }
  *(u32x4*)(xb + (size_t)w * 8) = o.v;
}

// Distributed readiness: two lanes poll each of the 32 flags of one batch
// quarter. Each flag owns a full 128B line -> 32 parallel line reads, no
// producer-side line ping-pong. SINGLE poller wave per block (round-7 showed
// 8 pollers/block re-creates the flag-line read storm).
__device__ __forceinline__ void wait_flags32(const int* f, int t)
{
  int l = threadIdx.x & 31;
  for (;;) {
    int v = __hip_atomic_load(&f[l * 32], __ATOMIC_RELAXED, __HIP_MEMORY_SCOPE_AGENT);
    if (__all(v >= t)) break;
  }
}

// ---------------------------------------------------------------------------
// Persistent part-LSTM, gate-in-lane formulation — FINAL (round-11 kernel,
// session best: plstm 1369us, total 1439.5us vs 1932us at session start).
//
// Design summary (what earned each piece its place, all HW-measured):
//  * 128 blocks x 512 threads; block = (bq=idx&3: batch quarter, XCD
//    co-located under the %8 dispatch heuristic) x (jgh=idx>>2: 16 hidden
//    cols). Wave = one 32x32x16 MFMA chain, jp = jgh*8+wv; weights resident
//    in 168 VGPRs (loaded once, UNCONDITIONALLY — conditional init demotes
//    to scratch, r9; adding ANY register state spills at this budget,
//    r10/r12: WRITE_SIZE 79.5->86MB with VGPR pinned at 128).
//  * flags: one 128B line each (r6, −55us: no producer line ping-pong).
//  * hall [t][bq:4][jgh:32][n:32][jl:16]: producer's 1KB publish = 8
//    exclusively-owned lines; consumer stage reads stay linear-contiguous
//    (r6; r8 proved scattered 1KB windows are worse, LDS write conflicts
//    in this map are hidden: 14.1M->4.3M conflicts changed nothing).
//  * publisher-exempt x-staging (r11, −46us): waves 1-7 cover all 768 x
//    chunks; wave 0's publish drain overlaps their staging, so its path to
//    barrier (A) is empty.
//  * wave-0-only flag poll + barrier release (r0/r7: more pollers = flag-
//    line read storm); x-MFMAs before the poll absorb inter-block jitter.
//  * per-step serial chain: stage x || drain -> (A) -> x-MFMA -> poll ->
//    (B0) -> stage h -> (B) -> 32 h-MFMA -> elementwise -> (C) -> publish.
//    Step floor ~4.56us = ~1.3us compute + ~3.2us h-exchange latency
//    (publish visibility + flag RTT + 32-producer skew) — latency-bound,
//    pipes ~75% idle; all structural neighbors measured worse (r1-r12).
// ---------------------------------------------------------------------------
__global__ void __launch_bounds__(512, 2)
plstm(const u16* __restrict__ xb, const u16* __restrict__ Wp,
      const float* __restrict__ bpack, u16* hall, int* flags,
      const float* __restrict__ fcw, const float* __restrict__ fcb,
      float* __restrict__ out)
{
  __shared__ __align__(16) u16 Hsh[32 * 512];   // 32 KB: h rows [n][64 chunks] (xor-swizzled)
  __shared__ __align__(16) u16 Xsh[32 * 256];   // 16 KB: x rows [n][32 chunks] (xor-swizzled)
  __shared__ __align__(16) u16 hbuf[32 * 16];   // 1 KB: h publish staging [n][jl]

  const int tid  = threadIdx.x;
  const int lane = tid & 63;
  const int wv   = tid >> 6;          // 8 waves
  const int n    = lane & 31;         // batch row within quarter
  const int hi   = lane >> 5;         // k-half / j-parity
  const int bq   = blockIdx.x & 3;    // 0..3  (XCD co-location remap)
  const int jgh  = blockIdx.x >> 2;   // 0..31 (16 j each)
  const int jp   = jgh * 8 + wv;      // j-pair 0..255
  const int j    = jp * 2 + hi;       // this lane's hidden col
  int* myflags = flags + bq * 1024;   // 32 flags * 32-int stride

  // resident A-fragments (weights), 42 ksteps x 4 VGPRs — unconditional load
  bf16x8 afr[42];
  {
    const u16* wpb = Wp + ((size_t)jp * 42 * 64 + lane) * 8;
    #pragma unroll
    for (int kk = 0; kk < 42; ++kk)
      afr[kk] = *(const bf16x8*)(wpb + kk * 512);
  }
  float bias[16];
  #pragma unroll
  for (int i = 0; i < 4; ++i)
    *(f32x4*)(bias + i * 4) = *(const f32x4*)(bpack + j * 16 + i * 4);

  float cst[5] = {0.f, 0.f, 0.f, 0.f, 0.f};

  for (int t = 0; t < T_SEQ; ++t) {
    // ---- waves 1-7: stage x[t] rows (own quarter) into LDS, chunk-XOR
    // swizzle. 448 threads cover 768 chunks (2 each, 2nd bounded). Wave 0
    // is EXEMPT: its publish drain from step t-1 overlaps this staging and
    // its path to (A) is empty. ((C) of step t-1 ordered all Xsh reads
    // before these writes.)
    if (wv >= 1) {
      const u16* xsrc = xb + (size_t)(t * 128 + bq * 32) * 192;
      int base = tid - 64;              // 0..447
      #pragma unroll
      for (int i = 0; i < 2; ++i) {
        int c = base + i * 448;         // 0..895, valid < 768 = 32 rows * 24 chunks
        if (c < 768) {
          int b = c / 24, cx = c - b * 24;
          u32x4 v = *(const u32x4*)(xsrc + b * 192 + (cx << 3));
          *(u32x4*)(Xsh + (b << 8) + (((cx ^ b) & 31) << 3)) = v;
        }
      }
    }
    __syncthreads();                      // (A)

    f32x16 acc;
    #pragma unroll
    for (int i = 0; i < 16; ++i) acc[i] = 0.f;

    // ---- K-loop, x part (no h dependency — absorbs inter-block jitter) ----
    #pragma unroll
    for (int kx = 0; kx < 10; ++kx) {
      int c = kx * 2 + hi;                // chunk 0..19
      bf16x8 bf = *(const bf16x8*)(Xsh + (n << 8) + (((c ^ n) & 31) << 3));
      acc = __builtin_amdgcn_mfma_f32_32x32x16_bf16(afr[32 + kx], bf, acc, 0, 0, 0);
    }

    // ---- wave 0 polls own-quarter flags; barrier release ----
    if (wv == 0) wait_flags32(myflags, t);
    __syncthreads();                      // (B0)

    // ---- stage h[t] (own quarter, block-major source, LINEAR in idx) into
    // LDS with the round-1 swizzle. idx rotated by jgh*64 so each block
    // starts at its own output's chunk group (L2-local first).
    {
      const u16* hsrc = hall + (size_t)t * 65536 + bq * 16384;
      #pragma unroll
      for (int i = 0; i < 4; ++i) {
        int idx = (tid + (i << 9) + (jgh << 6)) & 2047;  // 2048 chunks of 16B
        u32x4 v = *(const u32x4*)(hsrc + idx * 8);
        int nn = (idx >> 1) & 31;                        // batch row
        int cx = ((idx >> 6) << 1) | (idx & 1);          // logical chunk
        int phys = (cx & 32) | ((cx ^ nn) & 31);
        *(u32x4*)(Hsh + (nn << 9) + (phys << 3)) = v;
      }
    }
    __syncthreads();                      // (B)

    // ---- K-loop, hidden part ----
    #pragma unroll
    for (int kk = 0; kk < 32; ++kk) {
      int c = kk * 2 + hi;                // chunk 0..63
      int phys = (c & 32) | ((c ^ n) & 31);
      bf16x8 bf = *(const bf16x8*)(Hsh + (n << 9) + (phys << 3));
      acc = __builtin_amdgcn_mfma_f32_32x32x16_bf16(afr[kk], bf, acc, 0, 0, 0);
    }

    // ---- per-lane elementwise: acc[g] = gate g for (j, b) ----
    float cs = 0.f;
    #pragma unroll
    for (int p = 0; p < 5; ++p) {
      float iv = acc[p * 3 + 0] + bias[p * 3 + 0];
      float fv = acc[p * 3 + 1] + bias[p * 3 + 1];
      float gv = acc[p * 3 + 2] + bias[p * 3 + 2];
      cst[p] = sigf(fv) * cst[p] + sigf(iv) * tanh_f(gv);
      cs += cst[p];
    }
    float hv = sigf(acc[15] + bias[15]) * tanh_f(cs);

    // ---- publish h(t+1): LDS transpose -> contiguous 1KB (8 exclusive
    // lines) of agent-scope stores by wave 0; lane-local vmcnt drain; flag.
    // Waves 1-7 fall straight through to next step's x staging (overlap).
    hbuf[(n << 4) + (wv << 1) + hi] = f2bf(hv);
    __syncthreads();                      // (C)
    if (tid < 64) {
      const u16* src = hbuf + tid * 8;    // 16B per lane, linear
      u64 v0 = *(const u64*)(src);
      u64 v1 = *(const u64*)(src + 4);
      u64* dst = (u64*)(hall + (size_t)(t + 1) * 65536 + bq * 16384
                        + jgh * 512 + tid * 8);
      __hip_atomic_store(dst,     v0, __ATOMIC_RELAXED, __HIP_MEMORY_SCOPE_AGENT);
      __hip_atomic_store(dst + 1, v1, __ATOMIC_RELAXED, __HIP_MEMORY_SCOPE_AGENT);
      asm volatile("s_waitcnt vmcnt(0)" ::: "memory");   // wave-0-local drain
      if (tid == 0)
        __hip_atomic_store(&myflags[jgh * 32], t + 1, __ATOMIC_RELAXED, __HIP_MEMORY_SCOPE_AGENT);
    }
  }

  // ---- classifier + log_softmax: blocks 0..63 do 2 batch rows each ----
  if (blockIdx.x >= 64) return;
  for (;;) {
    int v0 = __hip_atomic_load(&flags[lane * 32],        __ATOMIC_RELAXED, __HIP_MEMORY_SCOPE_AGENT);
    int v1 = __hip_atomic_load(&flags[2048 + lane * 32], __ATOMIC_RELAXED, __HIP_MEMORY_SCOPE_AGENT);
    if (__all(min(v0, v1) >= T_SEQ)) break;
  }
  __syncthreads();
  float* fsh = (float*)Hsh;
  const u16* hT = hall + (size_t)T_SEQ * 65536;
  for (int r = 0; r < 2; ++r) {
    int row = blockIdx.x * 2 + r;
    int ks = tid >> 6, c = tid & 63;      // 8 K-slices of 64
    float s = 0.f;
    if (c < 60) {
      // hall element (row, j) -> [row>>5][j>>4][row&31][j&15]
      const u16* hb = hT + (row >> 5) * 16384 + (row & 31) * 16;
      const float* wr = fcw + (size_t)(ks * 64) * 60 + c;
      #pragma unroll 8
      for (int k = 0; k < 64; ++k)
        s += bf2f(hb[(ks * 4 + (k >> 4)) * 512 + (k & 15)]) * wr[k * 60];
    }
    __syncthreads();
    fsh[ks * 64 + c] = s;
    __syncthreads();
    if (tid < 60) {
      float lg = fcb[tid];
      #pragma unroll
      for (int i = 0; i < 8; ++i) lg += fsh[i * 64 + tid];
      fsh[512 + tid] = lg;
    }
    __syncthreads();
    if (tid == 0) {
      float mx = -1e30f;
      for (int i = 0; i < 60; ++i) mx = fmaxf(mx, fsh[512 + i]);
      float sm = 0.f;
      for (int i = 0; i < 60; ++i) sm += __expf(fsh[512 + i] - mx);
      fsh[576] = mx + __logf(sm);
    }
    __syncthreads();
    if (tid < 60) out[row * 60 + tid] = fsh[512 + tid] - fsh[576];
    __syncthreads();
  }
}

extern "C" void kernel_launch(void* const* d_in, const int* in_sizes, int n_in,
                              void* d_out, int out_size, void* d_ws, size_t ws_size,
                              hipStream_t stream)
{
  const float* xin = (const float*)d_in[0];   // [5][128][300][30]
  const float* Wx  = (const float*)d_in[1];   // [5][30][1536]
  const float* Wh  = (const float*)d_in[2];   // [5][512][1536]
  const float* bg  = (const float*)d_in[3];   // [5][1536]
  const float* Wxo = (const float*)d_in[4];   // [150][512]
  const float* Who = (const float*)d_in[5];   // [512][512]
  const float* bo  = (const float*)d_in[6];   // [512]
  const float* fcw = (const float*)d_in[7];   // [512][60]
  const float* fcb = (const float*)d_in[8];   // [60]
  float* out = (float*)d_out;                 // [128][60]

  char* ws = (char*)d_ws;
  u16*   Wp    = (u16*)(ws + OFF_WP);
  float* bpack = (float*)(ws + OFF_BP);
  u16*   xb    = (u16*)(ws + OFF_XB);
  u16*   hall  = (u16*)(ws + OFF_H);
  int*   flags = (int*)(ws + OFF_FL);

  hipLaunchKernelGGL(prep, dim3(2688), dim3(256), 0, stream,
                     Wx, Wh, bg, Wxo, Who, bo, Wp, bpack, hall, flags);
  hipLaunchKernelGGL(prep_x, dim3(3600), dim3(256), 0, stream, xin, xb);

  void* args[] = { (void*)&xb, (void*)&Wp, (void*)&bpack, (void*)&hall,
                   (void*)&flags, (void*)&fcw, (void*)&fcb, (void*)&out };
  hipLaunchCooperativeKernel((void*)plstm, dim3(128), dim3(512), args, 0, stream);
}